// Round 1
// baseline (1366.203 us; speedup 1.0000x reference)
//
#include <hip/hip_runtime.h>
#include <hip/hip_bf16.h>
#include <stdint.h>

#define NC 8192
#define GG 512

typedef __attribute__((ext_vector_type(8))) short bf16x8;   // 8 bf16 = 4 VGPRs (MFMA A/B frag)
typedef __attribute__((ext_vector_type(4))) float fx4;      // MFMA C/D frag

__device__ __forceinline__ float bf2f(short s){
  union { uint32_t u; float f; } c; c.u = ((uint32_t)(uint16_t)s) << 16; return c.f;
}
__device__ __forceinline__ short f2bf(float f){
  union { float f; uint32_t u; } c; c.f = f;
  uint32_t u = c.u;
  uint32_t r = (u + 0x7fffu + ((u >> 16) & 1u)) >> 16;   // RNE
  return (short)(uint16_t)r;
}
__device__ __forceinline__ void g2l16(const void* g, void* l){
  __builtin_amdgcn_global_load_lds((const __attribute__((address_space(1))) void*)g,
                                   (__attribute__((address_space(3))) void*)l, 16, 0, 0);
}

// ---------------- elementwise casts ----------------
__global__ void cast_f32_bf16(const float* __restrict__ in, short* __restrict__ out, int n){
  int i = (blockIdx.x * 256 + threadIdx.x) * 4;
  if (i < n){
    float4 v = *(const float4*)(in + i);
    uint32_t lo = (uint32_t)(uint16_t)f2bf(v.x) | ((uint32_t)(uint16_t)f2bf(v.y) << 16);
    uint32_t hi = (uint32_t)(uint16_t)f2bf(v.z) | ((uint32_t)(uint16_t)f2bf(v.w) << 16);
    *(uint2*)(out + i) = make_uint2(lo, hi);
  }
}

// in f32 [R][C] -> out bf16 [C][R]  (for B^T GEMM operands / transposed V)
__global__ void transpose_cast(const float* __restrict__ in, short* __restrict__ out, int R, int C){
  __shared__ float t[32][33];
  int c0 = blockIdx.x * 32, r0 = blockIdx.y * 32;
  int x = threadIdx.x & 31, y = threadIdx.x >> 5;  // y in 0..7
  #pragma unroll
  for (int it = 0; it < 4; ++it)
    t[y + 8*it][x] = in[(size_t)(r0 + y + 8*it) * C + c0 + x];
  __syncthreads();
  #pragma unroll
  for (int it = 0; it < 4; ++it)
    out[(size_t)(c0 + y + 8*it) * R + r0 + x] = f2bf(t[x][y + 8*it]);
}

// ---------------- main GEMM: C[M][N] = A[M][K] @ B[N][K]^T ----------------
// modes: 0 = tanh(c+bias) -> bf16 outb ; 1 = c+bias+res -> f32 outf ;
//        2 = outf = scale*c ; 3 = outf += scale*c
// BM=128 BN=64 BK=64, 4 waves as 2x2 of [64m x 32n], 16x16x32 bf16 MFMA.
// LDS rows are 128B (BK*2) => XOR-swizzle column chunks by (row&7) so ds_read_b128
// across 16 lanes is 2-way (free) instead of 16-way conflicted. Swizzle is applied
// to the GLOBAL address at staging (keeps lds dst = base + lane*16 contiguous).
__global__ __launch_bounds__(256, 2)
void gemm_bt(const short* __restrict__ A, int lda, const short* __restrict__ B, int ldb,
             int K, int mode, const float* __restrict__ bias,
             const float* __restrict__ res, int ldres,
             float* __restrict__ outf, short* __restrict__ outb, int ldo, float scale)
{
  __shared__ __align__(16) short As[128 * 64];
  __shared__ __align__(16) short Bs[64 * 64];
  const int tid = threadIdx.x;
  const int lane = tid & 63, wave = tid >> 6;
  const int wm = wave >> 1, wn = wave & 1;
  const int l16 = lane & 15, q = lane >> 4;
  const size_t i0 = (size_t)blockIdx.y * 128;
  const int n0 = blockIdx.x * 64;
  fx4 acc[4][2] = {};

  for (int k0 = 0; k0 < K; k0 += 64){
    #pragma unroll
    for (int inst = 0; inst < 4; ++inst){              // A tile 128x64 bf16 = 16KB
      int ch = inst * 256 + tid;
      int r = ch >> 3, pc = ch & 7;
      int colc = (pc ^ (r & 7)) * 8;
      g2l16(A + (i0 + r) * (size_t)lda + k0 + colc, As + ch * 8);
    }
    #pragma unroll
    for (int inst = 0; inst < 2; ++inst){              // B tile 64x64 bf16 = 8KB
      int ch = inst * 256 + tid;
      int r = ch >> 3, pc = ch & 7;
      int colc = (pc ^ (r & 7)) * 8;
      g2l16(B + (size_t)(n0 + r) * (size_t)ldb + k0 + colc, Bs + ch * 8);
    }
    __syncthreads();
    #pragma unroll
    for (int ks = 0; ks < 2; ++ks){
      int k8 = ks * 4 + q;
      bf16x8 af[4], bfr[2];
      #pragma unroll
      for (int mi = 0; mi < 4; ++mi){
        int r = wm * 64 + mi * 16 + l16;
        af[mi] = *(const bf16x8*)(As + r * 64 + ((k8 ^ (r & 7)) << 3));
      }
      #pragma unroll
      for (int ni = 0; ni < 2; ++ni){
        int r = wn * 32 + ni * 16 + l16;
        bfr[ni] = *(const bf16x8*)(Bs + r * 64 + ((k8 ^ (r & 7)) << 3));
      }
      #pragma unroll
      for (int mi = 0; mi < 4; ++mi)
        #pragma unroll
        for (int ni = 0; ni < 2; ++ni)
          acc[mi][ni] = __builtin_amdgcn_mfma_f32_16x16x32_bf16(af[mi], bfr[ni], acc[mi][ni], 0, 0, 0);
    }
    __syncthreads();
  }
  // epilogue: C frag layout col=lane&15 (n), row=q*4+r (m)
  #pragma unroll
  for (int mi = 0; mi < 4; ++mi){
    #pragma unroll
    for (int ni = 0; ni < 2; ++ni){
      int n = n0 + wn * 32 + ni * 16 + l16;
      float b = bias ? bias[n] : 0.0f;
      #pragma unroll
      for (int r = 0; r < 4; ++r){
        size_t m = i0 + wm * 64 + mi * 16 + q * 4 + r;
        float v = acc[mi][ni][r];
        size_t o = m * (size_t)ldo + n;
        if (mode == 0)      outb[o] = f2bf(tanhf(v + b));
        else if (mode == 1) outf[o] = v + b + res[m * (size_t)ldres + n];
        else if (mode == 2) outf[o] = v * scale;
        else                outf[o] += v * scale;
      }
    }
  }
}

// ---------------- score kernel: P[i][j] bf16 panel ----------------
// mode 0 (smooth): p = E[j]*exp(-sqrt(max(sq_i+sq_j-2*enc_i.enc_j,0))), l[i] += p
// mode 1 (sig):    p = sigmoid(Ah[i].enc[j])
// Computes S^T tiles (m-dim = j) so per-lane row stats stay per-i and the 4
// per-reg values are j-consecutive -> one 8B packed store per frag.
__global__ __launch_bounds__(256, 4)
void score_kernel(const short* __restrict__ encJ, const short* __restrict__ Bi,
                  const float* __restrict__ sq, const float* __restrict__ E,
                  float* __restrict__ l, short* __restrict__ P,
                  int panelJ, int jbase, int mode)
{
  const int tid = threadIdx.x, lane = tid & 63, wave = tid >> 6;
  const int l16 = lane & 15, q = lane >> 4;
  const int i0 = blockIdx.y * 32;
  const int jloc0 = blockIdx.x * 128 + wave * 32;
  const int jg0 = jbase + jloc0;

  bf16x8 bfr[2];
  #pragma unroll
  for (int nf = 0; nf < 2; ++nf)
    bfr[nf] = *(const bf16x8*)(Bi + (size_t)(i0 + nf * 16 + l16) * 32 + q * 8);
  float sqi[2] = {0.f, 0.f};
  if (mode == 0){ sqi[0] = sq[i0 + l16]; sqi[1] = sq[i0 + 16 + l16]; }
  float lacc[2] = {0.f, 0.f};

  #pragma unroll
  for (int mf = 0; mf < 2; ++mf){
    bf16x8 af = *(const bf16x8*)(encJ + (size_t)(jg0 + mf * 16 + l16) * 32 + q * 8);
    float4 sqj = make_float4(0,0,0,0), Ej = make_float4(0,0,0,0);
    if (mode == 0){
      sqj = *(const float4*)(sq + jg0 + mf * 16 + q * 4);
      Ej  = *(const float4*)(E  + jg0 + mf * 16 + q * 4);
    }
    #pragma unroll
    for (int nf = 0; nf < 2; ++nf){
      fx4 c = {};
      c = __builtin_amdgcn_mfma_f32_16x16x32_bf16(af, bfr[nf], c, 0, 0, 0);
      float pv[4];
      #pragma unroll
      for (int r = 0; r < 4; ++r){
        float dot = c[r];
        if (mode == 0){
          float sj = ((const float*)&sqj)[r];
          float ej = ((const float*)&Ej)[r];
          float d2 = fmaxf(sqi[nf] + sj - 2.0f * dot, 0.0f);
          float p = ej * __expf(-sqrtf(d2));
          lacc[nf] += p;
          pv[r] = p;
        } else {
          pv[r] = 1.0f / (1.0f + __expf(-dot));
        }
      }
      uint32_t lo = (uint32_t)(uint16_t)f2bf(pv[0]) | ((uint32_t)(uint16_t)f2bf(pv[1]) << 16);
      uint32_t hi = (uint32_t)(uint16_t)f2bf(pv[2]) | ((uint32_t)(uint16_t)f2bf(pv[3]) << 16);
      size_t iG = i0 + nf * 16 + l16;
      *(uint2*)(P + iG * (size_t)panelJ + jloc0 + mf * 16 + q * 4) = make_uint2(lo, hi);
    }
  }
  if (mode == 0){
    #pragma unroll
    for (int nf = 0; nf < 2; ++nf){
      float v = lacc[nf];
      v += __shfl_xor(v, 16);
      v += __shfl_xor(v, 32);
      if (lane < 16) atomicAdd(l + i0 + nf * 16 + lane, v);
    }
  }
}

// ---------------- small MLP tails ----------------
// enc = H2 @ eW2 + eb2 (bf16-rounded), sq = |enc|^2, Ah[h] = enc @ T[h]
__global__ void embed2_kernel(const short* __restrict__ H2, const float* __restrict__ eW2,
                              const float* __restrict__ eb2, const float* __restrict__ T4,
                              short* __restrict__ encb, float* __restrict__ sq,
                              short* __restrict__ Ah)
{
  __shared__ float encS[8][32];
  int d = threadIdx.x & 31, cl = threadIdx.x >> 5;
  size_t c = (size_t)blockIdx.x * 8 + cl;
  float s = eb2[d];
  const short* hrow = H2 + c * 256;
  for (int k = 0; k < 256; ++k) s += bf2f(hrow[k]) * eW2[k * 32 + d];
  short eb = f2bf(s);
  encb[c * 32 + d] = eb;
  encS[cl][d] = bf2f(eb);
  __syncthreads();
  if (d == 0){
    float t = 0;
    for (int k = 0; k < 32; ++k) t += encS[cl][k] * encS[cl][k];
    sq[c] = t;
  }
  #pragma unroll
  for (int h = 0; h < 4; ++h){
    float a = 0;
    const float* T = T4 + h * 1024;
    for (int k = 0; k < 32; ++k) a += encS[cl][k] * T[k * 32 + d];
    Ah[(size_t)h * NC * 32 + c * 32 + d] = f2bf(a);
  }
}

// E[c] = exp(quality[c]) ; quality = tanh(X@qW1+qb1)@qW2 + qb2
__global__ void quality_kernel(const float* __restrict__ X, const float* __restrict__ qW1,
                               const float* __restrict__ qb1, const float* __restrict__ qW2,
                               const float* __restrict__ qb2, float* __restrict__ E)
{
  int j = threadIdx.x & 63, cl = threadIdx.x >> 6;
  size_t c = (size_t)blockIdx.x * 4 + cl;
  float s = qb1[j];
  const float* xr = X + c * 512;
  for (int k = 0; k < 512; ++k) s += xr[k] * qW1[k * 64 + j];
  float t = tanhf(s) * qW2[j];
  #pragma unroll
  for (int o = 32; o >= 1; o >>= 1) t += __shfl_xor(t, o);
  if (j == 0) E[c] = __expf(t + qb2[0]);
}

__global__ void divide_kernel(const float* __restrict__ acc, const float* __restrict__ l,
                              float* __restrict__ smo, float* __restrict__ fin)
{
  size_t idx = ((size_t)blockIdx.x * 256 + threadIdx.x) * 4;
  int row = (int)(idx >> 9);
  float inv = 1.0f / l[row];
  float4 v = *(const float4*)(acc + idx);
  v.x *= inv; v.y *= inv; v.z *= inv; v.w *= inv;
  *(float4*)(smo + idx) = v;
  *(float4*)(fin + idx) = v;
}

// ---------------- host ----------------
extern "C" void kernel_launch(void* const* d_in, const int* in_sizes, int n_in,
                              void* d_out, int out_size, void* d_ws, size_t ws_size,
                              hipStream_t stream)
{
  const float* raw = (const float*)d_in[0];
  const float* dW1 = (const float*)d_in[1];
  const float* db1 = (const float*)d_in[2];
  const float* dW2 = (const float*)d_in[3];
  const float* db2 = (const float*)d_in[4];
  const float* eW1 = (const float*)d_in[5];
  const float* eb1 = (const float*)d_in[6];
  const float* eW2 = (const float*)d_in[7];
  const float* eb2 = (const float*)d_in[8];
  const float* qW1 = (const float*)d_in[9];
  const float* qb1 = (const float*)d_in[10];
  const float* qW2 = (const float*)d_in[11];
  const float* qb2 = (const float*)d_in[12];
  const float* Tr  = (const float*)d_in[13];
  const float* Gr  = (const float*)d_in[14];

  float* outD = (float*)d_out;                    // denoised [8192][512]
  float* outS = outD + (size_t)NC * GG;           // smoothed
  float* outF = outS + (size_t)NC * GG;           // final

  char* ws = (char*)d_ws;
  size_t off = 0;
  auto take = [&](size_t bytes) -> char* {
    char* p = ws + off; off += (bytes + 255) & ~(size_t)255; return p;
  };
  short* Xb   = (short*)take((size_t)NC * GG * 2);        // raw bf16 [cell][g]
  short* dW1T = (short*)take((size_t)512 * 512 * 2);
  short* dW2T = (short*)take((size_t)512 * 512 * 2);
  short* eW1T = (short*)take((size_t)256 * 512 * 2);
  short* GT   = (short*)take((size_t)4 * 512 * 512 * 2);  // gene_responses^T
  short* Hb   = (short*)take((size_t)NC * 512 * 2);       // hidden / U bf16 (reused)
  short* denT = (short*)take((size_t)GG * NC * 2);        // denoised^T [g][cell]
  short* smoT = (short*)take((size_t)GG * NC * 2);        // smoothed^T [g][cell]
  short* encb = (short*)take((size_t)NC * 32 * 2);
  short* Ahb  = (short*)take((size_t)4 * NC * 32 * 2);
  float* sqv  = (float*)take((size_t)NC * 4);
  float* Ev   = (float*)take((size_t)NC * 4);
  float* lv   = (float*)take((size_t)NC * 4);
  float* accv = (float*)take((size_t)NC * GG * 4);
  size_t fixedEnd = off;
  short* Pbuf = (short*)(ws + fixedEnd);

  int panelJ;
  {
    size_t avail = (ws_size > fixedEnd) ? (ws_size - fixedEnd) : 0;
    size_t mj = (avail / ((size_t)NC * 2)) & ~(size_t)127;
    if (mj >= (size_t)NC) panelJ = NC;
    else if (mj >= 128)   panelJ = (int)mj;
    else                  panelJ = 128;   // last resort
  }

  dim3 b256(256);
  // ---- casts / transposed weights ----
  cast_f32_bf16<<<dim3((NC * GG) / 1024), b256, 0, stream>>>(raw, Xb, NC * GG);
  transpose_cast<<<dim3(16, 16), b256, 0, stream>>>(dW1, dW1T, 512, 512);
  transpose_cast<<<dim3(16, 16), b256, 0, stream>>>(dW2, dW2T, 512, 512);
  transpose_cast<<<dim3(8, 16),  b256, 0, stream>>>(eW1, eW1T, 512, 256);
  for (int h = 0; h < 4; ++h)
    transpose_cast<<<dim3(16, 16), b256, 0, stream>>>(Gr + (size_t)h * 512 * 512,
                                                      GT + (size_t)h * 512 * 512, 512, 512);
  // ---- denoise MLP ----
  gemm_bt<<<dim3(8, 64), b256, 0, stream>>>(Xb, 512, dW1T, 512, 512, 0, db1,
                                            (const float*)nullptr, 0,
                                            (float*)nullptr, Hb, 512, 1.0f);
  gemm_bt<<<dim3(8, 64), b256, 0, stream>>>(Hb, 512, dW2T, 512, 512, 1, db2,
                                            raw, 512, outD, (short*)nullptr, 512, 1.0f);
  transpose_cast<<<dim3(16, 256), b256, 0, stream>>>(outD, denT, NC, 512);
  // ---- embed + quality ----
  gemm_bt<<<dim3(4, 64), b256, 0, stream>>>(Xb, 512, eW1T, 512, 512, 0, eb1,
                                            (const float*)nullptr, 0,
                                            (float*)nullptr, Hb, 256, 1.0f);
  embed2_kernel<<<dim3(NC / 8), b256, 0, stream>>>(Hb, eW2, eb2, Tr, encb, sqv, Ahb);
  quality_kernel<<<dim3(NC / 4), b256, 0, stream>>>(raw, qW1, qb1, qW2, qb2, Ev);
  // ---- smooth: acc = P @ denoised ; l = row sums ----
  hipMemsetAsync(lv, 0, NC * 4, stream);
  {
    bool first = true;
    for (int jb = 0; jb < NC; jb += panelJ){
      int jcnt = (NC - jb < panelJ) ? (NC - jb) : panelJ;
      score_kernel<<<dim3(jcnt / 128, NC / 32), b256, 0, stream>>>(
          encb, encb, sqv, Ev, lv, Pbuf, panelJ, jb, 0);
      gemm_bt<<<dim3(8, 64), b256, 0, stream>>>(Pbuf, panelJ, denT + jb, NC, jcnt,
                                                first ? 2 : 3, (const float*)nullptr,
                                                (const float*)nullptr, 0,
                                                accv, (short*)nullptr, 512, 1.0f);
      first = false;
    }
  }
  divide_kernel<<<dim3((NC * GG) / 1024), b256, 0, stream>>>(accv, lv, outS, outF);
  transpose_cast<<<dim3(16, 256), b256, 0, stream>>>(outS, smoT, NC, 512);
  // ---- interaction heads: final += (sigmoid(Ah.enc^T) @ smoothed) @ G_h / N ----
  for (int h = 0; h < 4; ++h){
    bool first = true;
    for (int jb = 0; jb < NC; jb += panelJ){
      int jcnt = (NC - jb < panelJ) ? (NC - jb) : panelJ;
      score_kernel<<<dim3(jcnt / 128, NC / 32), b256, 0, stream>>>(
          encb, Ahb + (size_t)h * NC * 32, sqv, Ev, (float*)nullptr, Pbuf, panelJ, jb, 1);
      gemm_bt<<<dim3(8, 64), b256, 0, stream>>>(Pbuf, panelJ, smoT + jb, NC, jcnt,
                                                first ? 2 : 3, (const float*)nullptr,
                                                (const float*)nullptr, 0,
                                                accv, (short*)nullptr, 512, 1.0f);
      first = false;
    }
    cast_f32_bf16<<<dim3((NC * GG) / 1024), b256, 0, stream>>>(accv, Hb, NC * GG);
    gemm_bt<<<dim3(8, 64), b256, 0, stream>>>(Hb, 512, GT + (size_t)h * 512 * 512, 512, 512,
                                              3, (const float*)nullptr,
                                              (const float*)nullptr, 0,
                                              outF, (short*)nullptr, 512, 1.0f / NC);
  }
}